// Round 1
// baseline (640.261 us; speedup 1.0000x reference)
//
#include <hip/hip_runtime.h>
#include <hip/hip_bf16.h>
#include <float.h>

// SplitNN: out1 = x1@W1+b1; sens = max-min of row-L1(out1); out1 += noise*sens*7.5;
// out1 *= rr_mask; out2 = x2@W2+b2; out = min(out1,out2)@Ws + bs
// B=262144, F=160, H=128, C=10, all fp32 in/out.
//
// Memory-bound: ~615 MB total HBM traffic across K1+K2 -> ~97us floor.
// Big matmuls via bf16 MFMA 16x16x32 (no fp32 MFMA on CDNA4); head matmul fp32 VALU.

typedef __bf16 bf16x8 __attribute__((ext_vector_type(8)));
typedef float  f32x4  __attribute__((ext_vector_type(4)));

#define WT_STRIDE 168   // 160 + 8 pad (keeps 16B alignment: 168*2=336 B rows)
#define NBLK 1024       // 4096 waves -> 4 slabs (of 16 rows) per wave

__global__ void k0_init(unsigned int* mmx) {
    if (threadIdx.x == 0) { mmx[0] = 0x7F7FFFFFu; /* FLT_MAX bits */ mmx[1] = 0u; }
}

__device__ __forceinline__ bf16x8 load_a_frag(const float* __restrict__ row, int k0) {
    const float4* p = (const float4*)(row + k0);
    float4 f0 = p[0], f1 = p[1];
    bf16x8 a;
    a[0] = (__bf16)f0.x; a[1] = (__bf16)f0.y; a[2] = (__bf16)f0.z; a[3] = (__bf16)f0.w;
    a[4] = (__bf16)f1.x; a[5] = (__bf16)f1.y; a[6] = (__bf16)f1.z; a[7] = (__bf16)f1.w;
    return a;
}

// K1: mm1 = x1@W1 + b1 (stored bf16 to ws), global min/max of row L1 norms via atomics.
__global__ __launch_bounds__(256, 2) void k1_sens(
    const float* __restrict__ x1, const float* __restrict__ W1,
    const float* __restrict__ b1, __hip_bfloat16* __restrict__ mm1,
    unsigned int* __restrict__ mmx, int B)
{
    __shared__ __align__(16) __bf16 wt[128 * WT_STRIDE];  // W1^T bf16 [n][k]
    __shared__ float smin[4], smax[4];
    for (int idx = threadIdx.x; idx < 160 * 128; idx += 256) {
        int k = idx >> 7, n = idx & 127;
        wt[n * WT_STRIDE + k] = (__bf16)W1[idx];
    }
    __syncthreads();

    const int lane = threadIdx.x & 63;
    const int wv   = threadIdx.x >> 6;
    const int m    = lane & 15;       // A-row / B-col / C-col index
    const int quad = lane >> 4;

    float b1v[8];
    #pragma unroll
    for (int ct = 0; ct < 8; ++ct) b1v[ct] = b1[ct * 16 + m];

    float wmin = FLT_MAX, wmax = 0.0f;
    const int nslab = B >> 4;
    for (int slab = blockIdx.x * 4 + wv; slab < nslab; slab += gridDim.x * 4) {
        const int r0 = slab << 4;
        f32x4 acc[8] = {};
        const float* arow = x1 + (size_t)(r0 + m) * 160 + quad * 8;
        #pragma unroll
        for (int ks = 0; ks < 5; ++ks) {
            bf16x8 a = load_a_frag(arow, ks * 32);
            #pragma unroll
            for (int ct = 0; ct < 8; ++ct) {
                bf16x8 bfr = *(const bf16x8*)&wt[(ct * 16 + m) * WT_STRIDE + ks * 32 + quad * 8];
                acc[ct] = __builtin_amdgcn_mfma_f32_16x16x32_bf16(a, bfr, acc[ct], 0, 0, 0);
            }
        }
        // C/D layout: col = lane&15, row = quad*4 + reg
        float ns[4] = {0.f, 0.f, 0.f, 0.f};
        #pragma unroll
        for (int ct = 0; ct < 8; ++ct) {
            #pragma unroll
            for (int reg = 0; reg < 4; ++reg) {
                float v = acc[ct][reg] + b1v[ct];
                mm1[(size_t)(r0 + quad * 4 + reg) * 128 + ct * 16 + m] = __float2bfloat16(v);
                ns[reg] += fabsf(v);
            }
        }
        // sum across the 16 lanes of each quad -> row L1 norms
        #pragma unroll
        for (int reg = 0; reg < 4; ++reg) {
            #pragma unroll
            for (int off = 1; off < 16; off <<= 1)
                ns[reg] += __shfl_xor(ns[reg], off, 64);
        }
        float mn = fminf(fminf(ns[0], ns[1]), fminf(ns[2], ns[3]));
        float mx = fmaxf(fmaxf(ns[0], ns[1]), fmaxf(ns[2], ns[3]));
        mn = fminf(mn, __shfl_xor(mn, 16, 64));
        mn = fminf(mn, __shfl_xor(mn, 32, 64));
        mx = fmaxf(mx, __shfl_xor(mx, 16, 64));
        mx = fmaxf(mx, __shfl_xor(mx, 32, 64));
        wmin = fminf(wmin, mn);
        wmax = fmaxf(wmax, mx);
    }
    if (lane == 0) { smin[wv] = wmin; smax[wv] = wmax; }
    __syncthreads();
    if (threadIdx.x == 0) {
        float bmin = fminf(fminf(smin[0], smin[1]), fminf(smin[2], smin[3]));
        float bmax = fmaxf(fmaxf(smax[0], smax[1]), fmaxf(smax[2], smax[3]));
        atomicMin(&mmx[0], __float_as_uint(bmin));  // norms >= 0: uint order == float order
        atomicMax(&mmx[1], __float_as_uint(bmax));
    }
}

// K2: out2 = x2@W2+b2 (MFMA); out1 = (mm1 + noise*mul)*mask; s = min; out = s@Ws + bs.
__global__ __launch_bounds__(256, 2) void k2_main(
    const float* __restrict__ x2, const float* __restrict__ W2,
    const float* __restrict__ b2, const float* __restrict__ Ws,
    const float* __restrict__ bs, const float* __restrict__ noise,
    const float* __restrict__ rru, const __hip_bfloat16* __restrict__ mm1,
    const unsigned int* __restrict__ mmx, float* __restrict__ out, int B)
{
    __shared__ __align__(16) __bf16 wt[128 * WT_STRIDE];  // W2^T bf16 [n][k]
    __shared__ float wst[10 * 128];                        // Ws^T fp32 [c10][h]
    for (int idx = threadIdx.x; idx < 160 * 128; idx += 256) {
        int k = idx >> 7, n = idx & 127;
        wt[n * WT_STRIDE + k] = (__bf16)W2[idx];
    }
    for (int idx = threadIdx.x; idx < 1280; idx += 256) {
        int h = idx / 10, c = idx - h * 10;
        wst[c * 128 + h] = Ws[idx];
    }
    __syncthreads();

    const float noise_mul = (__uint_as_float(mmx[1]) - __uint_as_float(mmx[0])) * 7.5f; // /EPS, EPS=4/30
    const int lane = threadIdx.x & 63;
    const int wv   = threadIdx.x >> 6;
    const int m    = lane & 15;
    const int quad = lane >> 4;

    float b2v[8], mk[8];
    #pragma unroll
    for (int ct = 0; ct < 8; ++ct) {
        b2v[ct] = b2[ct * 16 + m];
        mk[ct]  = (rru[ct * 16 + m] < 0.95f) ? 1.0f : 0.0f;
    }
    float bsv[10];
    #pragma unroll
    for (int c = 0; c < 10; ++c) bsv[c] = bs[c];

    const int nslab = B >> 4;
    for (int slab = blockIdx.x * 4 + wv; slab < nslab; slab += gridDim.x * 4) {
        const int r0 = slab << 4;
        f32x4 acc[8] = {};
        const float* arow = x2 + (size_t)(r0 + m) * 160 + quad * 8;
        #pragma unroll
        for (int ks = 0; ks < 5; ++ks) {
            bf16x8 a = load_a_frag(arow, ks * 32);
            #pragma unroll
            for (int ct = 0; ct < 8; ++ct) {
                bf16x8 bfr = *(const bf16x8*)&wt[(ct * 16 + m) * WT_STRIDE + ks * 32 + quad * 8];
                acc[ct] = __builtin_amdgcn_mfma_f32_16x16x32_bf16(a, bfr, acc[ct], 0, 0, 0);
            }
        }
        float s[8][4];
        #pragma unroll
        for (int ct = 0; ct < 8; ++ct) {
            #pragma unroll
            for (int reg = 0; reg < 4; ++reg) {
                const size_t idx = (size_t)(r0 + quad * 4 + reg) * 128 + ct * 16 + m;
                float v1 = (__bfloat162float(mm1[idx]) + noise[idx] * noise_mul) * mk[ct];
                float v2 = acc[ct][reg] + b2v[ct];
                s[ct][reg] = fminf(v1, v2);
            }
        }
        // head matmul: out[r][c10] = sum_h s[r][h]*Ws[h][c10]; reduce 16 lanes per quad
        #pragma unroll
        for (int c10 = 0; c10 < 10; ++c10) {
            float wsv[8];
            #pragma unroll
            for (int ct = 0; ct < 8; ++ct) wsv[ct] = wst[c10 * 128 + ct * 16 + m];
            float p[4];
            #pragma unroll
            for (int reg = 0; reg < 4; ++reg) {
                float a0 = 0.f;
                #pragma unroll
                for (int ct = 0; ct < 8; ++ct) a0 += s[ct][reg] * wsv[ct];
                #pragma unroll
                for (int off = 1; off < 16; off <<= 1)
                    a0 += __shfl_xor(a0, off, 64);
                p[reg] = a0;
            }
            if (m == c10) {
                #pragma unroll
                for (int reg = 0; reg < 4; ++reg)
                    out[(size_t)(r0 + quad * 4 + reg) * 10 + c10] = p[reg] + bsv[c10];
            }
        }
    }
}

extern "C" void kernel_launch(void* const* d_in, const int* in_sizes, int n_in,
                              void* d_out, int out_size, void* d_ws, size_t ws_size,
                              hipStream_t stream) {
    const float* x1    = (const float*)d_in[0];
    const float* x2    = (const float*)d_in[1];
    const float* W1    = (const float*)d_in[2];
    const float* b1    = (const float*)d_in[3];
    const float* W2    = (const float*)d_in[4];
    const float* b2    = (const float*)d_in[5];
    const float* Ws    = (const float*)d_in[6];
    const float* bs    = (const float*)d_in[7];
    const float* noise = (const float*)d_in[8];
    const float* rru   = (const float*)d_in[9];
    float* out = (float*)d_out;
    const int B = in_sizes[0] / 160;

    unsigned int*   mmx = (unsigned int*)d_ws;
    __hip_bfloat16* mm1 = (__hip_bfloat16*)((char*)d_ws + 256);  // B*128*2 bytes

    hipLaunchKernelGGL(k0_init, dim3(1), dim3(64), 0, stream, mmx);
    hipLaunchKernelGGL(k1_sens, dim3(NBLK), dim3(256), 0, stream, x1, W1, b1, mm1, mmx, B);
    hipLaunchKernelGGL(k2_main, dim3(NBLK), dim3(256), 0, stream,
                       x2, W2, b2, Ws, bs, noise, rru, mm1, mmx, out, B);
}